// Round 4
// baseline (415.437 us; speedup 1.0000x reference)
//
#include <hip/hip_runtime.h>
#include <hip/hip_bf16.h>

typedef __bf16 bf16;
typedef __bf16 bf16x4 __attribute__((ext_vector_type(4)));
typedef __bf16 bf16x8 __attribute__((ext_vector_type(8)));
typedef float floatx4 __attribute__((ext_vector_type(4)));

#define EMBED 1024
#define VOCAB 32000
#define BB    4
#define SS    4096
#define NTOK  (BB * SS)   // 16384
#define NKV   2048        // K and V concatenated
#define NSEG  16          // d-segments for partial-buffer GEMMs

// ---- async global->LDS, 16B per lane (lane-contiguous LDS dest required) ----
__device__ __forceinline__ void async_copy16(void* lds, const void* g) {
    __builtin_amdgcn_global_load_lds(
        (const __attribute__((address_space(1))) unsigned int*)g,
        (__attribute__((address_space(3))) unsigned int*)lds, 16, 0, 0);
}

// ============================================================================
// K1: gather h = embed[x] -> bf16; stash last token per batch (fp32) as both
// q-input (h_last) and residual init (h_final).
// ============================================================================
__global__ void gather_embed(const int* __restrict__ x,
                             const float* __restrict__ embed,
                             bf16* __restrict__ h,
                             float* __restrict__ h_last,
                             float* __restrict__ h_final) {
    int t = blockIdx.x;            // 16384 tokens
    int tid = threadIdx.x;         // 256
    int row = x[t];                // broadcast scalar load
    const float4* src = (const float4*)(embed + (size_t)row * EMBED);
    float4 v = src[tid];
    bf16x4 o; o.x = (bf16)v.x; o.y = (bf16)v.y; o.z = (bf16)v.z; o.w = (bf16)v.w;
    *(bf16x4*)(h + (size_t)t * EMBED + tid * 4) = o;
    if ((t & (SS - 1)) == SS - 1) {
        int b = t >> 12;
        *(float4*)(h_last  + b * EMBED + tid * 4) = v;
        *(float4*)(h_final + b * EMBED + tid * 4) = v;
    }
}

// ============================================================================
// K2: transpose+convert qkv_w[:, 1024:3072] -> WkvT[n][d] bf16 (2048 x 1024)
// ============================================================================
__global__ void wkvt_transpose(const float* __restrict__ qkv_w,
                               bf16* __restrict__ WkvT) {
    __shared__ float T[32][33];
    int n0 = blockIdx.x * 32, d0 = blockIdx.y * 32;
    int tid = threadIdx.x;
    int c = tid & 31, r = tid >> 5;
#pragma unroll
    for (int i = 0; i < 4; ++i) {
        int d = r + i * 8;
        T[c][d] = qkv_w[(size_t)(d0 + d) * (3 * EMBED) + EMBED + n0 + c];
    }
    __syncthreads();
#pragma unroll
    for (int i = 0; i < 4; ++i) {
        int n = r + i * 8;
        WkvT[(size_t)(n0 + n) * EMBED + d0 + c] = (bf16)T[n][c];
    }
}

// ============================================================================
// K3: q partials. qpart[seg][b][j] = sum_{d in seg} h_last[b][d]*qkv_w[d][j]
// ============================================================================
__global__ void q_gemm(const float* __restrict__ h_last,
                       const float* __restrict__ qkv_w,
                       float* __restrict__ qpart) {
    __shared__ float hs[BB * 64];
    int tid = threadIdx.x;
    int seg = blockIdx.x, d0 = seg * 64;
    hs[tid] = h_last[(tid >> 6) * EMBED + d0 + (tid & 63)];
    __syncthreads();
    int j0 = tid * 4;                           // 0..1023
    floatx4 acc[BB];
#pragma unroll
    for (int b = 0; b < BB; ++b) acc[b] = (floatx4)0.0f;
#pragma unroll 4
    for (int dd = 0; dd < 64; ++dd) {
        float4 w = *(const float4*)(qkv_w + (size_t)(d0 + dd) * (3 * EMBED) + j0);
#pragma unroll
        for (int b = 0; b < BB; ++b) {
            float hv = hs[b * 64 + dd];
            acc[b][0] += hv * w.x; acc[b][1] += hv * w.y;
            acc[b][2] += hv * w.z; acc[b][3] += hv * w.w;
        }
    }
#pragma unroll
    for (int b = 0; b < BB; ++b)
        *(floatx4*)(qpart + ((size_t)seg * BB + b) * EMBED + j0) = acc[b];
}

// K3b: q[b][d] = qkv_b[d] + sum_seg qpart[seg][b][d]
__global__ void q_reduce(const float* __restrict__ qpart,
                         const float* __restrict__ qkv_b,
                         float* __restrict__ q) {
    int k = blockIdx.x * 256 + threadIdx.x;     // 4096
    int b = k >> 10, d = k & (EMBED - 1);
    float s = qkv_b[d];
#pragma unroll
    for (int sg = 0; sg < NSEG; ++sg) s += qpart[((size_t)sg * BB + b) * EMBED + d];
    q[k] = s;
}

// ============================================================================
// K4: 256x256 tile, K in 32 halves of 32, 8 waves (2M x 4N), 4-slot LDS.
// v4: register double-buffered pipeline. v3 counters (MfmaUtil 33%, dur ==
// sum of LDS-cycles + MFMA-cycles) showed LDS reads and MFMA fully
// SERIALIZED: each half did reads -> lgkm -> MFMA in-wave, all waves
// phase-aligned. Fix: two fragment register sets; per half H issue
// ds_reads for H+1 (set B) then run MFMA(H) (set A) — no dependency, so
// the LDS pipe and matrix pipe overlap. One sync point per half:
//   sched_fence; lgkmcnt(0); vmcnt(8); s_barrier; sched_fence
// lgkm0 is ~free (reads had the whole MFMA block to finish) and makes the
// next iter's stage-overwrite of slot (H+1)&3 provably safe for all waves.
// vmcnt ledger (4 gload_lds per STG, prologue stages halves 0..3 = 16):
// steady: entering iter H outstanding = {H+2,H+3} (8); STG(H+4) -> 12;
// vmcnt(8) retires H+2. Tail: 8,8,4,0. RDF(H+1) at iter H needs half H+1:
// retired at end of iter H-1 by every wave (vmcnt(8) precedes barrier). ✓
// ============================================================================
__global__ __launch_bounds__(512, 1) void gemm_kv(
    const bf16* __restrict__ A,    // 16384 x 1024 row-major
    const bf16* __restrict__ BT,   // 2048 x 1024
    const float* __restrict__ bias,// 2048
    bf16* __restrict__ C) {        // 16384 x 2048
    __shared__ __align__(16) bf16 SA[4][8192];  // slot = half & 3
    __shared__ __align__(16) bf16 SB[4][8192];  // 128 KiB total

    const int tid  = threadIdx.x;          // 512
    const int wave = tid >> 6, lane = tid & 63;
    const int wm = wave >> 2, wn = wave & 3;        // 2 x 4 wave grid
    const int l16 = lane & 15, quad = lane >> 4;
    const int swz_l = (l16 & 3) ^ ((l16 >> 2) & 3);
    const int a_base = (wm * 128 + l16) * 32 + (quad ^ swz_l) * 8;
    const int b_base = (wn * 64  + l16) * 32 + (quad ^ swz_l) * 8;

    const bf16* Abase = A  + (size_t)blockIdx.x * 256 * EMBED;
    const bf16* Bbase = BT + (size_t)blockIdx.y * 256 * EMBED;

    floatx4 acc[8][4];
#pragma unroll
    for (int m = 0; m < 8; ++m)
#pragma unroll
        for (int n = 0; n < 4; ++n) acc[m][n] = (floatx4)0.0f;

    bf16x8 af0[4], af20[4], bf0[4];   // fragment set 0
    bf16x8 af1[4], af21[4], bf1[4];   // fragment set 1

// stage half H: k-range H*32..H*32+31 of both A and B tiles (4 gload_lds)
#define STG(H) do { \
    int c_ = wave * 128 + lane; \
    int r_ = c_ >> 2, sw_ = (r_ & 3) ^ ((r_ >> 2) & 3); \
    size_t go_ = (size_t)r_ * EMBED + (H) * 32 + ((c_ & 3) ^ sw_) * 8; \
    async_copy16(&SA[(H) & 3][c_ * 8], Abase + go_); \
    async_copy16(&SB[(H) & 3][c_ * 8], Bbase + go_); \
    c_ += 64; r_ = c_ >> 2; sw_ = (r_ & 3) ^ ((r_ >> 2) & 3); \
    go_ = (size_t)r_ * EMBED + (H) * 32 + ((c_ & 3) ^ sw_) * 8; \
    async_copy16(&SA[(H) & 3][c_ * 8], Abase + go_); \
    async_copy16(&SB[(H) & 3][c_ * 8], Bbase + go_); \
} while (0)

// read this wave's fragments of half H into a named register set
#define RDF(H, AF, AF2, BF) do { \
    const bf16* pa_ = &SA[(H) & 3][0] + a_base; \
    const bf16* pb_ = &SB[(H) & 3][0] + b_base; \
    _Pragma("unroll") \
    for (int i_ = 0; i_ < 4; ++i_) AF[i_]  = *(const bf16x8*)(pa_ + i_ * 512); \
    _Pragma("unroll") \
    for (int i_ = 0; i_ < 4; ++i_) BF[i_]  = *(const bf16x8*)(pb_ + i_ * 512); \
    _Pragma("unroll") \
    for (int i_ = 0; i_ < 4; ++i_) AF2[i_] = *(const bf16x8*)(pa_ + 2048 + i_ * 512); \
} while (0)

#define MFMAH(AF, AF2, BF) do { \
    __builtin_amdgcn_s_setprio(1); \
    _Pragma("unroll") \
    for (int mf_ = 0; mf_ < 4; ++mf_) \
    _Pragma("unroll") \
    for (int nf_ = 0; nf_ < 4; ++nf_) \
        acc[mf_][nf_] = __builtin_amdgcn_mfma_f32_16x16x32_bf16( \
            AF[mf_], BF[nf_], acc[mf_][nf_], 0, 0, 0); \
    _Pragma("unroll") \
    for (int mf_ = 0; mf_ < 4; ++mf_) \
    _Pragma("unroll") \
    for (int nf_ = 0; nf_ < 4; ++nf_) \
        acc[4 + mf_][nf_] = __builtin_amdgcn_mfma_f32_16x16x32_bf16( \
            AF2[mf_], BF[nf_], acc[4 + mf_][nf_], 0, 0, 0); \
    __builtin_amdgcn_s_setprio(0); \
} while (0)

#define SYNC(VM) do { \
    __builtin_amdgcn_sched_barrier(0); \
    asm volatile("s_waitcnt lgkmcnt(0)" ::: "memory"); \
    asm volatile("s_waitcnt vmcnt(" #VM ")" ::: "memory"); \
    __builtin_amdgcn_s_barrier(); \
    __builtin_amdgcn_sched_barrier(0); \
} while (0)

    // prologue: stage halves 0..3 (16 outstanding); half 0,1 resident after wait
    STG(0); STG(1); STG(2); STG(3);
    __builtin_amdgcn_sched_barrier(0);
    asm volatile("s_waitcnt vmcnt(8)" ::: "memory");
    __builtin_amdgcn_s_barrier();
    __builtin_amdgcn_sched_barrier(0);
    RDF(0, af0, af20, bf0);
    // extra barrier: all waves' RDF(0) reads complete before iter 0's STG(4)
    // overwrites slot 0
    __builtin_amdgcn_sched_barrier(0);
    asm volatile("s_waitcnt lgkmcnt(0)" ::: "memory");
    __builtin_amdgcn_s_barrier();
    __builtin_amdgcn_sched_barrier(0);

#pragma unroll 1
    for (int kk = 0; kk < 14; ++kk) {           // halves 0..27, stages 4..31
        const int H = 2 * kk;
        STG(H + 4);
        RDF(H + 1, af1, af21, bf1);
        MFMAH(af0, af20, bf0);
        SYNC(8);                                // retires half H+2
        STG(H + 5);
        RDF(H + 2, af0, af20, bf0);
        MFMAH(af1, af21, bf1);
        SYNC(8);                                // retires half H+3
    }
    // peeled tail: halves 28..31, no more staging
    RDF(29, af1, af21, bf1);
    MFMAH(af0, af20, bf0);
    SYNC(4);                                    // retires half 30
    RDF(30, af0, af20, bf0);
    MFMAH(af1, af21, bf1);
    SYNC(0);                                    // retires half 31
    RDF(31, af1, af21, bf1);
    MFMAH(af0, af20, bf0);
    MFMAH(af1, af21, bf1);                      // compiler lgkm-waits operands

    // epilogue: fragment fm covers rows fm*16.. within the wave's 128-row band
    const int crow0 = blockIdx.x * 256 + wm * 128;
    const int ccol0 = blockIdx.y * 256 + wn * 64;
    float bsv[4];
#pragma unroll
    for (int nf = 0; nf < 4; ++nf) bsv[nf] = bias[ccol0 + nf * 16 + l16];
#pragma unroll
    for (int fm = 0; fm < 8; ++fm)
#pragma unroll
        for (int nf = 0; nf < 4; ++nf) {
            int col = ccol0 + nf * 16 + l16;
#pragma unroll
            for (int r = 0; r < 4; ++r) {
                int row = crow0 + fm * 16 + quad * 4 + r;
                C[(size_t)row * NKV + col] = (bf16)(acc[fm][nf][r] + bsv[nf]);
            }
        }
#undef STG
#undef RDF
#undef MFMAH
#undef SYNC
}

// ============================================================================
// K5: logits[b][t] = (q[b] . K[b,t]) / 32 — one wave per t; q staged in LDS.
// ============================================================================
__global__ void attn_logits(const bf16* __restrict__ KV,
                            const float* __restrict__ q,
                            float* __restrict__ logits) {
    __shared__ float qs[EMBED];
    int b = blockIdx.x >> 10;                   // 1024 blocks per batch
    int t = (blockIdx.x & 1023) * 4 + (threadIdx.x >> 6);
    int lane = threadIdx.x & 63;
    *(float4*)(qs + threadIdx.x * 4) = *(const float4*)(q + b * EMBED + threadIdx.x * 4);
    __syncthreads();
    const bf16* Krow = KV + (size_t)(b * SS + t) * NKV;
    float sum = 0.0f;
#pragma unroll
    for (int i = 0; i < 2; ++i) {
        int d0 = i * 512 + lane * 8;
        bf16x8 kv8 = *(const bf16x8*)(Krow + d0);
        float4 qa = *(const float4*)(qs + d0);
        float4 qc = *(const float4*)(qs + d0 + 4);
        sum += qa.x * (float)kv8[0] + qa.y * (float)kv8[1] +
               qa.z * (float)kv8[2] + qa.w * (float)kv8[3] +
               qc.x * (float)kv8[4] + qc.y * (float)kv8[5] +
               qc.z * (float)kv8[6] + qc.w * (float)kv8[7];
    }
#pragma unroll
    for (int o = 32; o; o >>= 1) sum += __shfl_down(sum, o);
    if (lane == 0) logits[b * SS + t] = sum * 0.03125f;
}

// ============================================================================
// K6: softmax over 4096 per batch — one 1024-thread block per batch.
// ============================================================================
__global__ void softmax_k(const float* __restrict__ logits,
                          float* __restrict__ wts) {
    int b = blockIdx.x, tid = threadIdx.x;      // 1024 threads
    __shared__ float redm[16], reds[16];
    const float* l = logits + b * SS;
    float x0 = l[tid], x1 = l[tid + 1024], x2 = l[tid + 2048], x3 = l[tid + 3072];
    float m = fmaxf(fmaxf(x0, x1), fmaxf(x2, x3));
#pragma unroll
    for (int o = 32; o; o >>= 1) m = fmaxf(m, __shfl_down(m, o));
    if ((tid & 63) == 0) redm[tid >> 6] = m;
    __syncthreads();
    float M = redm[0];
#pragma unroll
    for (int i = 1; i < 16; ++i) M = fmaxf(M, redm[i]);
    float e0 = expf(x0 - M), e1 = expf(x1 - M), e2 = expf(x2 - M), e3 = expf(x3 - M);
    float s = e0 + e1 + e2 + e3;
#pragma unroll
    for (int o = 32; o; o >>= 1) s += __shfl_down(s, o);
    if ((tid & 63) == 0) reds[tid >> 6] = s;
    __syncthreads();
    float S = 0.0f;
#pragma unroll
    for (int i = 0; i < 16; ++i) S += reds[i];
    float inv = 1.0f / S;
    float* w = wts + b * SS;
    w[tid] = e0 * inv; w[tid + 1024] = e1 * inv;
    w[tid + 2048] = e2 * inv; w[tid + 3072] = e3 * inv;
}

// ============================================================================
// K7: avpart[b*64+ts][d] = sum_{t in ts-seg} wts[b][t] * V[b,t][d]
// ============================================================================
__global__ void attn_av(const bf16* __restrict__ KV,
                        const float* __restrict__ wts,
                        float* __restrict__ avpart) {
    int b = blockIdx.x >> 6, ts = blockIdx.x & 63;
    int tid = threadIdx.x;
    __shared__ float wsh[64];
    if (tid < 64) wsh[tid] = wts[b * SS + ts * 64 + tid];
    __syncthreads();
    int d = tid * 4;
    const bf16* Vb = KV + (size_t)(b * SS + ts * 64) * NKV + EMBED + d;
    float a0 = 0, a1 = 0, a2 = 0, a3 = 0;
#pragma unroll 4
    for (int j = 0; j < 64; ++j) {
        bf16x4 v = *(const bf16x4*)(Vb + (size_t)j * NKV);
        float w = wsh[j];
        a0 += w * (float)v.x; a1 += w * (float)v.y;
        a2 += w * (float)v.z; a3 += w * (float)v.w;
    }
    float4 o; o.x = a0; o.y = a1; o.z = a2; o.w = a3;
    *(float4*)(avpart + (size_t)(b * 64 + ts) * EMBED + d) = o;
}

// K7b: h_final[b][d] += sum_ts avpart[b*64+ts][d]
__global__ void av_reduce(const float* __restrict__ avpart,
                          float* __restrict__ h_final) {
    int i = blockIdx.x * 256 + threadIdx.x;     // 4096
    int b = i >> 10, d = i & (EMBED - 1);
    float s = 0.0f;
#pragma unroll
    for (int ts = 0; ts < 64; ++ts)
        s += avpart[(size_t)(b * 64 + ts) * EMBED + d];
    h_final[i] += s;
}

// ============================================================================
// K8: out partials. opart[seg][b][j] = sum_{d in seg} h_final[b][d]*out_w[d][j]
// ============================================================================
__global__ void out_gemm(const float* __restrict__ h_final,
                         const float* __restrict__ out_w,
                         float* __restrict__ opart) {
    __shared__ float hs[BB * 64];
    int tid = threadIdx.x;
    int seg = blockIdx.y, d0 = seg * 64;
    hs[tid] = h_final[(tid >> 6) * EMBED + d0 + (tid & 63)];
    __syncthreads();
    int j0 = blockIdx.x * 1024 + tid * 4;
    if (j0 >= VOCAB) return;                    // tail block: tid >= 64 idle
    floatx4 acc[BB];
#pragma unroll
    for (int b = 0; b < BB; ++b) acc[b] = (floatx4)0.0f;
#pragma unroll 4
    for (int dd = 0; dd < 64; ++dd) {
        float4 w = *(const float4*)(out_w + (size_t)(d0 + dd) * VOCAB + j0);
#pragma unroll
        for (int b = 0; b < BB; ++b) {
            float hv = hs[b * 64 + dd];
            acc[b][0] += hv * w.x; acc[b][1] += hv * w.y;
            acc[b][2] += hv * w.z; acc[b][3] += hv * w.w;
        }
    }
#pragma unroll
    for (int b = 0; b < BB; ++b)
        *(floatx4*)(opart + ((size_t)seg * BB + b) * VOCAB + j0) = acc[b];
}

// K8b: out[b][j] = out_b[j] + sum_seg opart[seg][b][j]
__global__ void out_reduce(const float* __restrict__ opart,
                           const float* __restrict__ out_b,
                           float* __restrict__ out) {
    int i = blockIdx.x * 256 + threadIdx.x;     // 128000
    if (i >= BB * VOCAB) return;
    int b = i / VOCAB, j = i - b * VOCAB;
    float s = out_b[j];
#pragma unroll
    for (int sg = 0; sg < NSEG; ++sg) s += opart[((size_t)sg * BB + b) * VOCAB + j];
    out[i] = s;
}

// ============================================================================
extern "C" void kernel_launch(void* const* d_in, const int* in_sizes, int n_in,
                              void* d_out, int out_size, void* d_ws, size_t ws_size,
                              hipStream_t stream) {
    const int*   x      = (const int*)d_in[0];
    const float* embed  = (const float*)d_in[1];
    const float* qkv_w  = (const float*)d_in[2];
    const float* qkv_b  = (const float*)d_in[3];
    const float* out_w  = (const float*)d_in[4];
    const float* out_b  = (const float*)d_in[5];
    float* out = (float*)d_out;

    char* ws = (char*)d_ws;
    bf16*  h       = (bf16*)(ws);                         // 32 MiB
    float* avpart  = (float*)(ws);                        // 1 MiB, overlays h (h dead after gemm_kv)
    float* opart   = (float*)(ws);                        // 8 MiB, overlays avpart (dead after av_reduce)
    bf16*  KV      = (bf16*)(ws + 33554432);              // 64 MiB
    bf16*  WkvT    = (bf16*)(ws + 100663296);             // 4 MiB
    float* h_last  = (float*)(ws + 104857600);            // 16 KiB
    float* h_final = (float*)(ws + 104873984);            // 16 KiB
    float* q       = (float*)(ws + 104890368);            // 16 KiB
    float* logits  = (float*)(ws + 104906752);            // 64 KiB
    float* wts     = (float*)(ws + 104972288);            // 64 KiB
    float* qpart   = (float*)(ws + 105037824);            // 256 KiB

    gather_embed<<<NTOK, 256, 0, stream>>>(x, embed, h, h_last, h_final);
    wkvt_transpose<<<dim3(64, 32), 256, 0, stream>>>(qkv_w, WkvT);
    q_gemm<<<NSEG, 256, 0, stream>>>(h_last, qkv_w, qpart);
    q_reduce<<<16, 256, 0, stream>>>(qpart, qkv_b, q);
    gemm_kv<<<dim3(NTOK / 256, NKV / 256), 512, 0, stream>>>(
        h, WkvT, qkv_b + EMBED, KV);
    attn_logits<<<SS, 256, 0, stream>>>(KV, q, logits);
    softmax_k<<<BB, 1024, 0, stream>>>(logits, wts);
    attn_av<<<256, 256, 0, stream>>>(KV, wts, avpart);
    av_reduce<<<16, 256, 0, stream>>>(avpart, h_final);
    out_gemm<<<dim3(32, NSEG), 256, 0, stream>>>(h_final, out_w, opart);
    out_reduce<<<(BB * VOCAB + 255) / 256, 256, 0, stream>>>(opart, out_b, out);
}

// Round 5
// 390.599 us; speedup vs baseline: 1.0636x; 1.0636x over previous
//
#include <hip/hip_runtime.h>
#include <hip/hip_bf16.h>

typedef __bf16 bf16;
typedef __bf16 bf16x4 __attribute__((ext_vector_type(4)));
typedef __bf16 bf16x8 __attribute__((ext_vector_type(8)));
typedef float floatx4 __attribute__((ext_vector_type(4)));

#define EMBED 1024
#define VOCAB 32000
#define BB    4
#define SS    4096
#define NTOK  (BB * SS)   // 16384
#define NKV   2048        // K and V concatenated
#define NSEG  16          // d-segments for the q partial GEMM

// ---- async global->LDS, 16B per lane (lane-contiguous LDS dest required) ----
__device__ __forceinline__ void async_copy16(void* lds, const void* g) {
    __builtin_amdgcn_global_load_lds(
        (const __attribute__((address_space(1))) unsigned int*)g,
        (__attribute__((address_space(3))) unsigned int*)lds, 16, 0, 0);
}

// ============================================================================
// K1 "prep": merged gather_embed + wkvt_transpose + q_gemm (all independent).
// Launch-count reduction: 3 kernels -> 1; the three jobs are dispatched by
// blockIdx range. q_gemm reads embed[x[last]] directly (not h_last), so there
// is NO cross-block dependency inside the merged kernel.
//   blocks [0, 16384)          : gather h = embed[x] -> bf16; last-token rows
//                                also seed h_final (fp32 residual init).
//   blocks [16384, 18432)      : transpose+convert qkv_w[:,1024:3072] -> WkvT
//   blocks [18432, 18448)      : q partials over d-segments of 64
// ============================================================================
__global__ void prep(const int* __restrict__ x,
                     const float* __restrict__ embed,
                     const float* __restrict__ qkv_w,
                     bf16* __restrict__ h,
                     float* __restrict__ h_final,
                     bf16* __restrict__ WkvT,
                     float* __restrict__ qpart) {
    __shared__ float T[32][33];     // wkvt branch
    __shared__ float hs[BB * 64];   // q_gemm branch
    const int blk = blockIdx.x, tid = threadIdx.x;

    if (blk < NTOK) {
        // ---- gather ----
        int row = x[blk];           // broadcast scalar load
        const float4* src = (const float4*)(embed + (size_t)row * EMBED);
        float4 v = src[tid];
        bf16x4 o; o.x = (bf16)v.x; o.y = (bf16)v.y; o.z = (bf16)v.z; o.w = (bf16)v.w;
        *(bf16x4*)(h + (size_t)blk * EMBED + tid * 4) = o;
        if ((blk & (SS - 1)) == SS - 1) {
            int b = blk >> 12;
            *(float4*)(h_final + b * EMBED + tid * 4) = v;
        }
    } else if (blk < NTOK + 2048) {
        // ---- WkvT transpose ----
        int idx = blk - NTOK;
        int n0 = (idx & 63) * 32, d0 = (idx >> 6) * 32;
        int c = tid & 31, r = tid >> 5;
#pragma unroll
        for (int i = 0; i < 4; ++i) {
            int d = r + i * 8;
            T[c][d] = qkv_w[(size_t)(d0 + d) * (3 * EMBED) + EMBED + n0 + c];
        }
        __syncthreads();
#pragma unroll
        for (int i = 0; i < 4; ++i) {
            int n = r + i * 8;
            WkvT[(size_t)(n0 + n) * EMBED + d0 + c] = (bf16)T[n][c];
        }
    } else {
        // ---- q partials: qpart[seg][b][j] = sum_{d in seg} h_last[b][d]*qkv_w[d][j]
        //      h_last[b][d] == embed[x[(b+1)*SS-1]][d], read directly.
        int seg = blk - (NTOK + 2048), d0 = seg * 64;
        int b = tid >> 6;
        int lrow = x[((b + 1) << 12) - 1];
        hs[tid] = embed[(size_t)lrow * EMBED + d0 + (tid & 63)];
        __syncthreads();
        int j0 = tid * 4;                           // 0..1023
        floatx4 acc[BB];
#pragma unroll
        for (int bb = 0; bb < BB; ++bb) acc[bb] = (floatx4)0.0f;
#pragma unroll 4
        for (int dd = 0; dd < 64; ++dd) {
            float4 w = *(const float4*)(qkv_w + (size_t)(d0 + dd) * (3 * EMBED) + j0);
#pragma unroll
            for (int bb = 0; bb < BB; ++bb) {
                float hv = hs[bb * 64 + dd];
                acc[bb][0] += hv * w.x; acc[bb][1] += hv * w.y;
                acc[bb][2] += hv * w.z; acc[bb][3] += hv * w.w;
            }
        }
#pragma unroll
        for (int bb = 0; bb < BB; ++bb)
            *(floatx4*)(qpart + ((size_t)seg * BB + bb) * EMBED + j0) = acc[bb];
    }
}

// K1b: q[b][d] = qkv_b[d] + sum_seg qpart[seg][b][d]
__global__ void q_reduce(const float* __restrict__ qpart,
                         const float* __restrict__ qkv_b,
                         float* __restrict__ q) {
    int k = blockIdx.x * 256 + threadIdx.x;     // 4096
    int b = k >> 10, d = k & (EMBED - 1);
    float s = qkv_b[d];
#pragma unroll
    for (int sg = 0; sg < NSEG; ++sg) s += qpart[((size_t)sg * BB + b) * EMBED + d];
    q[k] = s;
}

// ============================================================================
// K4: 256x256 tile, K in 32 halves of 32, 8 waves (2M x 4N), 4-slot LDS.
// v3 schedule (best measured: 85.9 us, 799 TF) — kept verbatim. v4's
// register double-buffering regressed (97 us); schedule experiments paused.
// One barrier per k-half; counted vmcnt(8) steady-state, tail 8/8/4/0.
// ============================================================================
__global__ __launch_bounds__(512, 1) void gemm_kv(
    const bf16* __restrict__ A,    // 16384 x 1024 row-major
    const bf16* __restrict__ BT,   // 2048 x 1024
    const float* __restrict__ bias,// 2048
    bf16* __restrict__ C) {        // 16384 x 2048
    __shared__ __align__(16) bf16 SA[2][2][256 * 32];  // [khalf][parity][row*32+k]
    __shared__ __align__(16) bf16 SB[2][2][256 * 32];  // 128 KiB total

    const int tid  = threadIdx.x;          // 512
    const int wave = tid >> 6, lane = tid & 63;
    const int wm = wave >> 2, wn = wave & 3;        // 2 x 4 wave grid
    const int l16 = lane & 15, quad = lane >> 4;
    const int swz_l = (l16 & 3) ^ ((l16 >> 2) & 3);
    const int a_base = (wm * 128 + l16) * 32 + (quad ^ swz_l) * 8;
    const int b_base = (wn * 64  + l16) * 32 + (quad ^ swz_l) * 8;

    const bf16* Abase = A  + (size_t)blockIdx.x * 256 * EMBED;
    const bf16* Bbase = BT + (size_t)blockIdx.y * 256 * EMBED;

    floatx4 acc[8][4];
#pragma unroll
    for (int m = 0; m < 8; ++m)
#pragma unroll
        for (int n = 0; n < 4; ++n) acc[m][n] = (floatx4)0.0f;

    bf16x8 af[4], af2[4], bfr[4];

#define STG(KH, KT) do { \
    int c_ = wave * 128 + lane; \
    int r_ = c_ >> 2, sw_ = (r_ & 3) ^ ((r_ >> 2) & 3); \
    size_t go_ = (size_t)r_ * EMBED + (KT) * 64 + (KH) * 32 + ((c_ & 3) ^ sw_) * 8; \
    async_copy16(&SA[KH][(KT) & 1][c_ * 8], Abase + go_); \
    async_copy16(&SB[KH][(KT) & 1][c_ * 8], Bbase + go_); \
    c_ += 64; r_ = c_ >> 2; sw_ = (r_ & 3) ^ ((r_ >> 2) & 3); \
    go_ = (size_t)r_ * EMBED + (KT) * 64 + (KH) * 32 + ((c_ & 3) ^ sw_) * 8; \
    async_copy16(&SA[KH][(KT) & 1][c_ * 8], Abase + go_); \
    async_copy16(&SB[KH][(KT) & 1][c_ * 8], Bbase + go_); \
} while (0)

#define NOSTG() do { } while (0)

#define HSTEP(KH, PAR, STG_BODY, WN) do { \
    __builtin_amdgcn_sched_barrier(0); \
    asm volatile("s_waitcnt vmcnt(" #WN ")" ::: "memory"); \
    __builtin_amdgcn_s_barrier(); \
    __builtin_amdgcn_sched_barrier(0); \
    STG_BODY; \
    { const bf16* pa_ = &SA[KH][PAR][a_base]; \
      const bf16* pb_ = &SB[KH][PAR][b_base]; \
      _Pragma("unroll") \
      for (int i_ = 0; i_ < 4; ++i_) af [i_] = *(const bf16x8*)(pa_ + i_ * 512); \
      _Pragma("unroll") \
      for (int i_ = 0; i_ < 4; ++i_) bfr[i_] = *(const bf16x8*)(pb_ + i_ * 512); \
      _Pragma("unroll") \
      for (int i_ = 0; i_ < 4; ++i_) af2[i_] = *(const bf16x8*)(pa_ + 2048 + i_ * 512); } \
    __builtin_amdgcn_s_setprio(1); \
    _Pragma("unroll") \
    for (int mf_ = 0; mf_ < 4; ++mf_) \
    _Pragma("unroll") \
    for (int nf_ = 0; nf_ < 4; ++nf_) \
        acc[mf_][nf_] = __builtin_amdgcn_mfma_f32_16x16x32_bf16( \
            af[mf_], bfr[nf_], acc[mf_][nf_], 0, 0, 0); \
    _Pragma("unroll") \
    for (int mf_ = 0; mf_ < 4; ++mf_) \
    _Pragma("unroll") \
    for (int nf_ = 0; nf_ < 4; ++nf_) \
        acc[4 + mf_][nf_] = __builtin_amdgcn_mfma_f32_16x16x32_bf16( \
            af2[mf_], bfr[nf_], acc[4 + mf_][nf_], 0, 0, 0); \
    __builtin_amdgcn_s_setprio(0); \
} while (0)

    // prologue: stage halves 0,1,2 = (t0,kh0),(t0,kh1),(t1,kh0) -> 12 in flight
    STG(0, 0); STG(1, 0); STG(0, 1);

#pragma unroll 1
    for (int kk = 0; kk < 7; ++kk) {            // tiles 0..13 (halves 0..27)
        const int t1 = 2 * kk + 1;
        HSTEP(0, 0, STG(1, t1),     8);         // stage half H+3 = (t1,   kh1)
        HSTEP(1, 0, STG(0, t1 + 1), 8);         //                  (t1+1, kh0)
        HSTEP(0, 1, STG(1, t1 + 1), 8);         //                  (t1+1, kh1)
        HSTEP(1, 1, STG(0, t1 + 2), 8);         //                  (t1+2, kh0)
    }
    // tiles 14,15 (halves 28..31); stages remaining: half 31 only
    HSTEP(0, 0, STG(1, 15), 8);
    HSTEP(1, 0, NOSTG(),    8);
    HSTEP(0, 1, NOSTG(),    4);
    HSTEP(1, 1, NOSTG(),    0);

    // epilogue: fragment fm covers rows fm*16.. within the wave's 128-row band
    const int crow0 = blockIdx.x * 256 + wm * 128;
    const int ccol0 = blockIdx.y * 256 + wn * 64;
    float bsv[4];
#pragma unroll
    for (int nf = 0; nf < 4; ++nf) bsv[nf] = bias[ccol0 + nf * 16 + l16];
#pragma unroll
    for (int fm = 0; fm < 8; ++fm)
#pragma unroll
        for (int nf = 0; nf < 4; ++nf) {
            int col = ccol0 + nf * 16 + l16;
#pragma unroll
            for (int r = 0; r < 4; ++r) {
                int row = crow0 + fm * 16 + quad * 4 + r;
                C[(size_t)row * NKV + col] = (bf16)(acc[fm][nf][r] + bsv[nf]);
            }
        }
#undef STG
#undef NOSTG
#undef HSTEP
}

// ============================================================================
// K5: logits[b][t] = (q[b] . K[b,t]) / 32 — one wave per t; q staged in LDS.
// ============================================================================
__global__ void attn_logits(const bf16* __restrict__ KV,
                            const float* __restrict__ q,
                            float* __restrict__ logits) {
    __shared__ float qs[EMBED];
    int b = blockIdx.x >> 10;                   // 1024 blocks per batch
    int t = (blockIdx.x & 1023) * 4 + (threadIdx.x >> 6);
    int lane = threadIdx.x & 63;
    *(float4*)(qs + threadIdx.x * 4) = *(const float4*)(q + b * EMBED + threadIdx.x * 4);
    __syncthreads();
    const bf16* Krow = KV + (size_t)(b * SS + t) * NKV;
    float sum = 0.0f;
#pragma unroll
    for (int i = 0; i < 2; ++i) {
        int d0 = i * 512 + lane * 8;
        bf16x8 kv8 = *(const bf16x8*)(Krow + d0);
        float4 qa = *(const float4*)(qs + d0);
        float4 qc = *(const float4*)(qs + d0 + 4);
        sum += qa.x * (float)kv8[0] + qa.y * (float)kv8[1] +
               qa.z * (float)kv8[2] + qa.w * (float)kv8[3] +
               qc.x * (float)kv8[4] + qc.y * (float)kv8[5] +
               qc.z * (float)kv8[6] + qc.w * (float)kv8[7];
    }
#pragma unroll
    for (int o = 32; o; o >>= 1) sum += __shfl_down(sum, o);
    if (lane == 0) logits[b * SS + t] = sum * 0.03125f;
}

// ============================================================================
// K6: softmax over 4096 per batch — one 1024-thread block per batch.
// ============================================================================
__global__ void softmax_k(const float* __restrict__ logits,
                          float* __restrict__ wts) {
    int b = blockIdx.x, tid = threadIdx.x;      // 1024 threads
    __shared__ float redm[16], reds[16];
    const float* l = logits + b * SS;
    float x0 = l[tid], x1 = l[tid + 1024], x2 = l[tid + 2048], x3 = l[tid + 3072];
    float m = fmaxf(fmaxf(x0, x1), fmaxf(x2, x3));
#pragma unroll
    for (int o = 32; o; o >>= 1) m = fmaxf(m, __shfl_down(m, o));
    if ((tid & 63) == 0) redm[tid >> 6] = m;
    __syncthreads();
    float M = redm[0];
#pragma unroll
    for (int i = 1; i < 16; ++i) M = fmaxf(M, redm[i]);
    float e0 = expf(x0 - M), e1 = expf(x1 - M), e2 = expf(x2 - M), e3 = expf(x3 - M);
    float s = e0 + e1 + e2 + e3;
#pragma unroll
    for (int o = 32; o; o >>= 1) s += __shfl_down(s, o);
    if ((tid & 63) == 0) reds[tid >> 6] = s;
    __syncthreads();
    float S = 0.0f;
#pragma unroll
    for (int i = 0; i < 16; ++i) S += reds[i];
    float inv = 1.0f / S;
    float* w = wts + b * SS;
    w[tid] = e0 * inv; w[tid + 1024] = e1 * inv;
    w[tid + 2048] = e2 * inv; w[tid + 3072] = e3 * inv;
}

// ============================================================================
// K7: h_final[b] += sum_t wts[b][t] * V[b,t] — v1 atomic form (measured
// better than the partials+reduce split, and one fewer launch).
// ============================================================================
__global__ void attn_av(const bf16* __restrict__ KV,
                        const float* __restrict__ wts,
                        float* __restrict__ h_final) {
    int b = blockIdx.x >> 6, ts = blockIdx.x & 63;
    int tid = threadIdx.x;
    __shared__ float wsh[64];
    if (tid < 64) wsh[tid] = wts[b * SS + ts * 64 + tid];
    __syncthreads();
    int d = tid * 4;
    const bf16* Vb = KV + (size_t)(b * SS + ts * 64) * NKV + EMBED + d;
    float a0 = 0, a1 = 0, a2 = 0, a3 = 0;
#pragma unroll 4
    for (int j = 0; j < 64; ++j) {
        bf16x4 v = *(const bf16x4*)(Vb + (size_t)j * NKV);
        float w = wsh[j];
        a0 += w * (float)v.x; a1 += w * (float)v.y;
        a2 += w * (float)v.z; a3 += w * (float)v.w;
    }
    atomicAdd(h_final + b * EMBED + d + 0, a0);
    atomicAdd(h_final + b * EMBED + d + 1, a1);
    atomicAdd(h_final + b * EMBED + d + 2, a2);
    atomicAdd(h_final + b * EMBED + d + 3, a3);
}

// ============================================================================
// K8: fused output GEMM, no partials. out[b][j] = out_b[j] + h_final[b].out_w[:,j]
// grid = 500 blocks x 64 cols. 4 row-bands per block (r = tid>>6), each thread
// sums 256 rows x 4 batches; LDS band-reduce; single write. Kills the 16 MB
// opart round-trip and one launch.
// ============================================================================
__global__ void out_gemm2(const float* __restrict__ h_final,
                          const float* __restrict__ out_w,
                          const float* __restrict__ out_b,
                          float* __restrict__ out) {
    __shared__ float hs[BB * EMBED];            // 16 KB
    __shared__ float red[4][BB][64];            // 4 KB
    int tid = threadIdx.x;
    int j0 = blockIdx.x * 64;
#pragma unroll
    for (int i = 0; i < BB * EMBED; i += 256) hs[i + tid] = h_final[i + tid];
    __syncthreads();
    int col = tid & 63, r = tid >> 6;
    int j = j0 + col;
    float a0 = 0, a1 = 0, a2 = 0, a3 = 0;
#pragma unroll 4
    for (int i = 0; i < 256; ++i) {
        int d = r + i * 4;
        float w = out_w[(size_t)d * VOCAB + j];
        a0 += hs[d] * w;
        a1 += hs[EMBED + d] * w;
        a2 += hs[2 * EMBED + d] * w;
        a3 += hs[3 * EMBED + d] * w;
    }
    red[r][0][col] = a0; red[r][1][col] = a1;
    red[r][2][col] = a2; red[r][3][col] = a3;
    __syncthreads();
    int b = tid >> 6;                           // reuse 256 threads: 4b x 64col
    float s = out_b[j0 + col] +
              red[0][b][col] + red[1][b][col] + red[2][b][col] + red[3][b][col];
    out[b * VOCAB + j0 + col] = s;
}

// ============================================================================
extern "C" void kernel_launch(void* const* d_in, const int* in_sizes, int n_in,
                              void* d_out, int out_size, void* d_ws, size_t ws_size,
                              hipStream_t stream) {
    const int*   x      = (const int*)d_in[0];
    const float* embed  = (const float*)d_in[1];
    const float* qkv_w  = (const float*)d_in[2];
    const float* qkv_b  = (const float*)d_in[3];
    const float* out_w  = (const float*)d_in[4];
    const float* out_b  = (const float*)d_in[5];
    float* out = (float*)d_out;

    char* ws = (char*)d_ws;
    bf16*  h       = (bf16*)(ws);                         // 32 MiB
    bf16*  KV      = (bf16*)(ws + 33554432);              // 64 MiB
    bf16*  WkvT    = (bf16*)(ws + 100663296);             // 4 MiB
    float* h_final = (float*)(ws + 104873984);            // 16 KiB
    float* q       = (float*)(ws + 104890368);            // 16 KiB
    float* logits  = (float*)(ws + 104906752);            // 64 KiB
    float* wts     = (float*)(ws + 104972288);            // 64 KiB
    float* qpart   = (float*)(ws + 105037824);            // 256 KiB

    prep<<<NTOK + 2048 + NSEG, 256, 0, stream>>>(x, embed, qkv_w, h, h_final, WkvT, qpart);
    q_reduce<<<16, 256, 0, stream>>>(qpart, qkv_b, q);
    gemm_kv<<<dim3(NTOK / 256, NKV / 256), 512, 0, stream>>>(
        h, WkvT, qkv_b + EMBED, KV);
    attn_logits<<<SS, 256, 0, stream>>>(KV, q, logits);
    softmax_k<<<BB, 1024, 0, stream>>>(logits, wts);
    attn_av<<<256, 256, 0, stream>>>(KV, wts, h_final);
    out_gemm2<<<VOCAB / 64, 256, 0, stream>>>(h_final, out_w, out_b, out);
}

// Round 6
// 390.253 us; speedup vs baseline: 1.0645x; 1.0009x over previous
//
#include <hip/hip_runtime.h>
#include <hip/hip_bf16.h>

typedef __bf16 bf16;
typedef __bf16 bf16x4 __attribute__((ext_vector_type(4)));
typedef __bf16 bf16x8 __attribute__((ext_vector_type(8)));
typedef float floatx4 __attribute__((ext_vector_type(4)));

#define EMBED 1024
#define VOCAB 32000
#define BB    4
#define SS    4096
#define NTOK  (BB * SS)   // 16384
#define NKV   2048        // K and V concatenated
#define NSEG  16          // d-segments for the q partial GEMM

// ---- async global->LDS, 16B per lane (lane-contiguous LDS dest required) ----
__device__ __forceinline__ void async_copy16(void* lds, const void* g) {
    __builtin_amdgcn_global_load_lds(
        (const __attribute__((address_space(1))) unsigned int*)g,
        (__attribute__((address_space(3))) unsigned int*)lds, 16, 0, 0);
}

// ============================================================================
// K1 "prep": merged gather_embed + wkvt_transpose + q_gemm (all independent).
//   blocks [0, 16384)          : gather h = embed[x] -> bf16; last-token rows
//                                also seed h_final (fp32 residual init).
//   blocks [16384, 18432)      : transpose+convert qkv_w[:,1024:3072] -> WkvT
//   blocks [18432, 18448)      : q partials over d-segments of 64
// ============================================================================
__global__ void prep(const int* __restrict__ x,
                     const float* __restrict__ embed,
                     const float* __restrict__ qkv_w,
                     bf16* __restrict__ h,
                     float* __restrict__ h_final,
                     bf16* __restrict__ WkvT,
                     float* __restrict__ qpart) {
    __shared__ float T[32][33];     // wkvt branch
    __shared__ float hs[BB * 64];   // q_gemm branch
    const int blk = blockIdx.x, tid = threadIdx.x;

    if (blk < NTOK) {
        // ---- gather ----
        int row = x[blk];           // broadcast scalar load
        const float4* src = (const float4*)(embed + (size_t)row * EMBED);
        float4 v = src[tid];
        bf16x4 o; o.x = (bf16)v.x; o.y = (bf16)v.y; o.z = (bf16)v.z; o.w = (bf16)v.w;
        *(bf16x4*)(h + (size_t)blk * EMBED + tid * 4) = o;
        if ((blk & (SS - 1)) == SS - 1) {
            int b = blk >> 12;
            *(float4*)(h_final + b * EMBED + tid * 4) = v;
        }
    } else if (blk < NTOK + 2048) {
        // ---- WkvT transpose ----
        int idx = blk - NTOK;
        int n0 = (idx & 63) * 32, d0 = (idx >> 6) * 32;
        int c = tid & 31, r = tid >> 5;
#pragma unroll
        for (int i = 0; i < 4; ++i) {
            int d = r + i * 8;
            T[c][d] = qkv_w[(size_t)(d0 + d) * (3 * EMBED) + EMBED + n0 + c];
        }
        __syncthreads();
#pragma unroll
        for (int i = 0; i < 4; ++i) {
            int n = r + i * 8;
            WkvT[(size_t)(n0 + n) * EMBED + d0 + c] = (bf16)T[n][c];
        }
    } else {
        // ---- q partials ----
        int seg = blk - (NTOK + 2048), d0 = seg * 64;
        int b = tid >> 6;
        int lrow = x[((b + 1) << 12) - 1];
        hs[tid] = embed[(size_t)lrow * EMBED + d0 + (tid & 63)];
        __syncthreads();
        int j0 = tid * 4;                           // 0..1023
        floatx4 acc[BB];
#pragma unroll
        for (int bb = 0; bb < BB; ++bb) acc[bb] = (floatx4)0.0f;
#pragma unroll 4
        for (int dd = 0; dd < 64; ++dd) {
            float4 w = *(const float4*)(qkv_w + (size_t)(d0 + dd) * (3 * EMBED) + j0);
#pragma unroll
            for (int bb = 0; bb < BB; ++bb) {
                float hv = hs[bb * 64 + dd];
                acc[bb][0] += hv * w.x; acc[bb][1] += hv * w.y;
                acc[bb][2] += hv * w.z; acc[bb][3] += hv * w.w;
            }
        }
#pragma unroll
        for (int bb = 0; bb < BB; ++bb)
            *(floatx4*)(qpart + ((size_t)seg * BB + bb) * EMBED + j0) = acc[bb];
    }
}

// K1b: q[b][d] = qkv_b[d] + sum_seg qpart[seg][b][d]
__global__ void q_reduce(const float* __restrict__ qpart,
                         const float* __restrict__ qkv_b,
                         float* __restrict__ q) {
    int k = blockIdx.x * 256 + threadIdx.x;     // 4096
    int b = k >> 10, d = k & (EMBED - 1);
    float s = qkv_b[d];
#pragma unroll
    for (int sg = 0; sg < NSEG; ++sg) s += qpart[((size_t)sg * BB + b) * EMBED + d];
    q[k] = s;
}

// ============================================================================
// K4: 256x256 tile, K in 32 halves of 32, 8 waves (2M x 4N), 4-slot LDS.
// v3 schedule (best measured: 85.9 us) — code unchanged; now launched as TWO
// half-grids (rows 0-8191, 8192-16383) purely as a top-5 VISIBILITY probe:
// each dispatch ~43 us drops the profiling top-5 threshold so second-tier
// kernels (30-84 us, currently invisible) must surface next round.
// ============================================================================
__global__ __launch_bounds__(512, 1) void gemm_kv(
    const bf16* __restrict__ A,    // 8192 x 1024 row-major (half)
    const bf16* __restrict__ BT,   // 2048 x 1024
    const float* __restrict__ bias,// 2048
    bf16* __restrict__ C) {        // 8192 x 2048 (half)
    __shared__ __align__(16) bf16 SA[2][2][256 * 32];  // [khalf][parity][row*32+k]
    __shared__ __align__(16) bf16 SB[2][2][256 * 32];  // 128 KiB total

    const int tid  = threadIdx.x;          // 512
    const int wave = tid >> 6, lane = tid & 63;
    const int wm = wave >> 2, wn = wave & 3;        // 2 x 4 wave grid
    const int l16 = lane & 15, quad = lane >> 4;
    const int swz_l = (l16 & 3) ^ ((l16 >> 2) & 3);
    const int a_base = (wm * 128 + l16) * 32 + (quad ^ swz_l) * 8;
    const int b_base = (wn * 64  + l16) * 32 + (quad ^ swz_l) * 8;

    const bf16* Abase = A  + (size_t)blockIdx.x * 256 * EMBED;
    const bf16* Bbase = BT + (size_t)blockIdx.y * 256 * EMBED;

    floatx4 acc[8][4];
#pragma unroll
    for (int m = 0; m < 8; ++m)
#pragma unroll
        for (int n = 0; n < 4; ++n) acc[m][n] = (floatx4)0.0f;

    bf16x8 af[4], af2[4], bfr[4];

#define STG(KH, KT) do { \
    int c_ = wave * 128 + lane; \
    int r_ = c_ >> 2, sw_ = (r_ & 3) ^ ((r_ >> 2) & 3); \
    size_t go_ = (size_t)r_ * EMBED + (KT) * 64 + (KH) * 32 + ((c_ & 3) ^ sw_) * 8; \
    async_copy16(&SA[KH][(KT) & 1][c_ * 8], Abase + go_); \
    async_copy16(&SB[KH][(KT) & 1][c_ * 8], Bbase + go_); \
    c_ += 64; r_ = c_ >> 2; sw_ = (r_ & 3) ^ ((r_ >> 2) & 3); \
    go_ = (size_t)r_ * EMBED + (KT) * 64 + (KH) * 32 + ((c_ & 3) ^ sw_) * 8; \
    async_copy16(&SA[KH][(KT) & 1][c_ * 8], Abase + go_); \
    async_copy16(&SB[KH][(KT) & 1][c_ * 8], Bbase + go_); \
} while (0)

#define NOSTG() do { } while (0)

#define HSTEP(KH, PAR, STG_BODY, WN) do { \
    __builtin_amdgcn_sched_barrier(0); \
    asm volatile("s_waitcnt vmcnt(" #WN ")" ::: "memory"); \
    __builtin_amdgcn_s_barrier(); \
    __builtin_amdgcn_sched_barrier(0); \
    STG_BODY; \
    { const bf16* pa_ = &SA[KH][PAR][a_base]; \
      const bf16* pb_ = &SB[KH][PAR][b_base]; \
      _Pragma("unroll") \
      for (int i_ = 0; i_ < 4; ++i_) af [i_] = *(const bf16x8*)(pa_ + i_ * 512); \
      _Pragma("unroll") \
      for (int i_ = 0; i_ < 4; ++i_) bfr[i_] = *(const bf16x8*)(pb_ + i_ * 512); \
      _Pragma("unroll") \
      for (int i_ = 0; i_ < 4; ++i_) af2[i_] = *(const bf16x8*)(pa_ + 2048 + i_ * 512); } \
    __builtin_amdgcn_s_setprio(1); \
    _Pragma("unroll") \
    for (int mf_ = 0; mf_ < 4; ++mf_) \
    _Pragma("unroll") \
    for (int nf_ = 0; nf_ < 4; ++nf_) \
        acc[mf_][nf_] = __builtin_amdgcn_mfma_f32_16x16x32_bf16( \
            af[mf_], bfr[nf_], acc[mf_][nf_], 0, 0, 0); \
    _Pragma("unroll") \
    for (int mf_ = 0; mf_ < 4; ++mf_) \
    _Pragma("unroll") \
    for (int nf_ = 0; nf_ < 4; ++nf_) \
        acc[4 + mf_][nf_] = __builtin_amdgcn_mfma_f32_16x16x32_bf16( \
            af2[mf_], bfr[nf_], acc[4 + mf_][nf_], 0, 0, 0); \
    __builtin_amdgcn_s_setprio(0); \
} while (0)

    // prologue: stage halves 0,1,2 = (t0,kh0),(t0,kh1),(t1,kh0) -> 12 in flight
    STG(0, 0); STG(1, 0); STG(0, 1);

#pragma unroll 1
    for (int kk = 0; kk < 7; ++kk) {            // tiles 0..13 (halves 0..27)
        const int t1 = 2 * kk + 1;
        HSTEP(0, 0, STG(1, t1),     8);         // stage half H+3 = (t1,   kh1)
        HSTEP(1, 0, STG(0, t1 + 1), 8);         //                  (t1+1, kh0)
        HSTEP(0, 1, STG(1, t1 + 1), 8);         //                  (t1+1, kh1)
        HSTEP(1, 1, STG(0, t1 + 2), 8);         //                  (t1+2, kh0)
    }
    // tiles 14,15 (halves 28..31); stages remaining: half 31 only
    HSTEP(0, 0, STG(1, 15), 8);
    HSTEP(1, 0, NOSTG(),    8);
    HSTEP(0, 1, NOSTG(),    4);
    HSTEP(1, 1, NOSTG(),    0);

    // epilogue
    const int crow0 = blockIdx.x * 256 + wm * 128;
    const int ccol0 = blockIdx.y * 256 + wn * 64;
    float bsv[4];
#pragma unroll
    for (int nf = 0; nf < 4; ++nf) bsv[nf] = bias[ccol0 + nf * 16 + l16];
#pragma unroll
    for (int fm = 0; fm < 8; ++fm)
#pragma unroll
        for (int nf = 0; nf < 4; ++nf) {
            int col = ccol0 + nf * 16 + l16;
#pragma unroll
            for (int r = 0; r < 4; ++r) {
                int row = crow0 + fm * 16 + quad * 4 + r;
                C[(size_t)row * NKV + col] = (bf16)(acc[fm][nf][r] + bsv[nf]);
            }
        }
#undef STG
#undef NOSTG
#undef HSTEP
}

// ============================================================================
// K5: logits[b][t] = (q[b] . K[b,t]) / 32 — one wave per t; q staged in LDS.
// ============================================================================
__global__ void attn_logits(const bf16* __restrict__ KV,
                            const float* __restrict__ q,
                            float* __restrict__ logits) {
    __shared__ float qs[EMBED];
    int b = blockIdx.x >> 10;                   // 1024 blocks per batch
    int t = (blockIdx.x & 1023) * 4 + (threadIdx.x >> 6);
    int lane = threadIdx.x & 63;
    *(float4*)(qs + threadIdx.x * 4) = *(const float4*)(q + b * EMBED + threadIdx.x * 4);
    __syncthreads();
    const bf16* Krow = KV + (size_t)(b * SS + t) * NKV;
    float sum = 0.0f;
#pragma unroll
    for (int i = 0; i < 2; ++i) {
        int d0 = i * 512 + lane * 8;
        bf16x8 kv8 = *(const bf16x8*)(Krow + d0);
        float4 qa = *(const float4*)(qs + d0);
        float4 qc = *(const float4*)(qs + d0 + 4);
        sum += qa.x * (float)kv8[0] + qa.y * (float)kv8[1] +
               qa.z * (float)kv8[2] + qa.w * (float)kv8[3] +
               qc.x * (float)kv8[4] + qc.y * (float)kv8[5] +
               qc.z * (float)kv8[6] + qc.w * (float)kv8[7];
    }
#pragma unroll
    for (int o = 32; o; o >>= 1) sum += __shfl_down(sum, o);
    if (lane == 0) logits[b * SS + t] = sum * 0.03125f;
}

// ============================================================================
// K6: softmax over 4096 per batch — one 1024-thread block per batch.
// ============================================================================
__global__ void softmax_k(const float* __restrict__ logits,
                          float* __restrict__ wts) {
    int b = blockIdx.x, tid = threadIdx.x;      // 1024 threads
    __shared__ float redm[16], reds[16];
    const float* l = logits + b * SS;
    float x0 = l[tid], x1 = l[tid + 1024], x2 = l[tid + 2048], x3 = l[tid + 3072];
    float m = fmaxf(fmaxf(x0, x1), fmaxf(x2, x3));
#pragma unroll
    for (int o = 32; o; o >>= 1) m = fmaxf(m, __shfl_down(m, o));
    if ((tid & 63) == 0) redm[tid >> 6] = m;
    __syncthreads();
    float M = redm[0];
#pragma unroll
    for (int i = 1; i < 16; ++i) M = fmaxf(M, redm[i]);
    float e0 = expf(x0 - M), e1 = expf(x1 - M), e2 = expf(x2 - M), e3 = expf(x3 - M);
    float s = e0 + e1 + e2 + e3;
#pragma unroll
    for (int o = 32; o; o >>= 1) s += __shfl_down(s, o);
    if ((tid & 63) == 0) reds[tid >> 6] = s;
    __syncthreads();
    float S = 0.0f;
#pragma unroll
    for (int i = 0; i < 16; ++i) S += reds[i];
    float inv = 1.0f / S;
    float* w = wts + b * SS;
    w[tid] = e0 * inv; w[tid + 1024] = e1 * inv;
    w[tid + 2048] = e2 * inv; w[tid + 3072] = e3 * inv;
}

// ============================================================================
// K7: h_final[b] += sum_t wts[b][t] * V[b,t] — atomic form.
// ============================================================================
__global__ void attn_av(const bf16* __restrict__ KV,
                        const float* __restrict__ wts,
                        float* __restrict__ h_final) {
    int b = blockIdx.x >> 6, ts = blockIdx.x & 63;
    int tid = threadIdx.x;
    __shared__ float wsh[64];
    if (tid < 64) wsh[tid] = wts[b * SS + ts * 64 + tid];
    __syncthreads();
    int d = tid * 4;
    const bf16* Vb = KV + (size_t)(b * SS + ts * 64) * NKV + EMBED + d;
    float a0 = 0, a1 = 0, a2 = 0, a3 = 0;
#pragma unroll 4
    for (int j = 0; j < 64; ++j) {
        bf16x4 v = *(const bf16x4*)(Vb + (size_t)j * NKV);
        float w = wsh[j];
        a0 += w * (float)v.x; a1 += w * (float)v.y;
        a2 += w * (float)v.z; a3 += w * (float)v.w;
    }
    atomicAdd(h_final + b * EMBED + d + 0, a0);
    atomicAdd(h_final + b * EMBED + d + 1, a1);
    atomicAdd(h_final + b * EMBED + d + 2, a2);
    atomicAdd(h_final + b * EMBED + d + 3, a3);
}

// ============================================================================
// K8 v2: fused output GEMM. v1 (500 blocks, unroll-4) was latency-bound:
// 2 blocks/CU x 8 waves x 4 loads in flight = ~12 GB/s/CU << 24.6 needed for
// the 131 MB out_w stream. v2: 1000 blocks x 32 cols, 8 r-bands, unroll-8 ->
// 4 blocks/CU, 16 waves, ~8 loads in flight per wave -> BW-floor (~22 us).
// ============================================================================
__global__ void out_gemm2(const float* __restrict__ h_final,
                          const float* __restrict__ out_w,
                          const float* __restrict__ out_b,
                          float* __restrict__ out) {
    __shared__ float hs[BB * EMBED];            // 16 KB
    __shared__ float red[8][BB][32];            // 4 KB
    int tid = threadIdx.x;
    int j0 = blockIdx.x * 32;
#pragma unroll
    for (int i = 0; i < BB * EMBED; i += 256) hs[i + tid] = h_final[i + tid];
    __syncthreads();
    int col = tid & 31, r = tid >> 5;           // 8 row-bands
    int j = j0 + col;
    float a0 = 0, a1 = 0, a2 = 0, a3 = 0;
#pragma unroll 8
    for (int i = 0; i < 128; ++i) {
        int d = r + i * 8;
        float w = out_w[(size_t)d * VOCAB + j];
        a0 += hs[d] * w;
        a1 += hs[EMBED + d] * w;
        a2 += hs[2 * EMBED + d] * w;
        a3 += hs[3 * EMBED + d] * w;
    }
    red[r][0][col] = a0; red[r][1][col] = a1;
    red[r][2][col] = a2; red[r][3][col] = a3;
    __syncthreads();
    if (tid < 128) {
        int b = tid >> 5, c = tid & 31;
        float s = out_b[j0 + c];
#pragma unroll
        for (int rr = 0; rr < 8; ++rr) s += red[rr][b][c];
        out[b * VOCAB + j0 + c] = s;
    }
}

// ============================================================================
extern "C" void kernel_launch(void* const* d_in, const int* in_sizes, int n_in,
                              void* d_out, int out_size, void* d_ws, size_t ws_size,
                              hipStream_t stream) {
    const int*   x      = (const int*)d_in[0];
    const float* embed  = (const float*)d_in[1];
    const float* qkv_w  = (const float*)d_in[2];
    const float* qkv_b  = (const float*)d_in[3];
    const float* out_w  = (const float*)d_in[4];
    const float* out_b  = (const float*)d_in[5];
    float* out = (float*)d_out;

    char* ws = (char*)d_ws;
    bf16*  h       = (bf16*)(ws);                         // 32 MiB
    bf16*  KV      = (bf16*)(ws + 33554432);              // 64 MiB
    bf16*  WkvT    = (bf16*)(ws + 100663296);             // 4 MiB
    float* h_final = (float*)(ws + 104873984);            // 16 KiB
    float* q       = (float*)(ws + 104890368);            // 16 KiB
    float* logits  = (float*)(ws + 104906752);            // 64 KiB
    float* wts     = (float*)(ws + 104972288);            // 64 KiB
    float* qpart   = (float*)(ws + 105037824);            // 256 KiB

    prep<<<NTOK + 2048 + NSEG, 256, 0, stream>>>(x, embed, qkv_w, h, h_final, WkvT, qpart);
    q_reduce<<<16, 256, 0, stream>>>(qpart, qkv_b, q);
    // split into two half-grids: visibility probe (drops top-5 threshold)
    gemm_kv<<<dim3(NTOK / 512, NKV / 256), 512, 0, stream>>>(
        h, WkvT, qkv_b + EMBED, KV);
    gemm_kv<<<dim3(NTOK / 512, NKV / 256), 512, 0, stream>>>(
        h + (size_t)(NTOK / 2) * EMBED, WkvT, qkv_b + EMBED,
        KV + (size_t)(NTOK / 2) * NKV);
    attn_logits<<<SS, 256, 0, stream>>>(KV, q, logits);
    softmax_k<<<BB, 1024, 0, stream>>>(logits, wts);
    attn_av<<<256, 256, 0, stream>>>(KV, wts, h_final);
    out_gemm2<<<VOCAB / 32, 256, 0, stream>>>(h_final, out_w, out_b, out);
}